// Round 1
// baseline (1346.392 us; speedup 1.0000x reference)
//
#include <hip/hip_runtime.h>

// Problem constants (fixed by the reference setup)
constexpr int H = 512, W = 512;
constexpr int P = H * W;          // 262144 pixels
constexpr int NSP = 1024;         // superpixels
constexpr int SBLK = 64;          // scatter partial blocks

// ---------------- conv1: 1 -> 64, ReLU ----------------
__global__ __launch_bounds__(256) void conv1_k(const float* __restrict__ raw,
                                               const float* __restrict__ w1,
                                               const float* __restrict__ b1,
                                               float* __restrict__ h1) {
  int pix = blockIdx.x * 256 + threadIdx.x;
  int r = pix >> 9, c = pix & 511;
  float in[9];
#pragma unroll
  for (int ky = 0; ky < 3; ++ky)
#pragma unroll
    for (int kx = 0; kx < 3; ++kx) {
      int rr = r + ky - 1, cc = c + kx - 1;
      bool ok = ((unsigned)rr < (unsigned)H) && ((unsigned)cc < (unsigned)W);
      in[ky * 3 + kx] = ok ? raw[rr * W + cc] : 0.f;
    }
#pragma unroll 8
  for (int oc = 0; oc < 64; ++oc) {
    float acc = b1[oc];
#pragma unroll
    for (int k = 0; k < 9; ++k) acc = fmaf(in[k], w1[oc * 9 + k], acc);
    h1[oc * P + pix] = fmaxf(acc, 0.f);
  }
}

// ---------------- convN: 64 -> COUT, optional ReLU ----------------
// Direct conv, 32x8 pixel tile per 256-thread block, ic staged in LDS
// in chunks of 32 channels. Weights w[oc][ic][3][3] read as wave-uniform
// scalar loads. Accumulators fully unrolled (static indices only).
template <int COUT, bool RELU>
__global__ __launch_bounds__(256) void convN_k(const float* __restrict__ x,
                                               const float* __restrict__ w,
                                               const float* __restrict__ b,
                                               float* __restrict__ y) {
  constexpr int TX = 32, TY = 8;
  constexpr int ICCH = 32;
  constexpr int LROW = TX + 2;          // 34
  constexpr int LPLANE = (TY + 2) * LROW;  // 340
  __shared__ float lin[ICCH * LPLANE];  // 43520 B

  int tid = threadIdx.x;
  int tilex = blockIdx.x & 15;          // W/TX = 16
  int tiley = blockIdx.x >> 4;          // H/TY = 64
  int c0 = tilex * TX, r0 = tiley * TY;
  int tx = tid & 31, ty = tid >> 5;

  float acc[COUT];
#pragma unroll
  for (int oc = 0; oc < COUT; ++oc) acc[oc] = b[oc];

  for (int ic0 = 0; ic0 < 64; ic0 += ICCH) {
    __syncthreads();
    // stage ICCH channels of the (TY+2)x(TX+2) halo tile
    for (int idx = tid; idx < ICCH * LPLANE; idx += 256) {
      int ic = idx / LPLANE;
      int rem = idx - ic * LPLANE;
      int ly = rem / LROW;
      int lx = rem - ly * LROW;
      int gr = r0 + ly - 1, gc = c0 + lx - 1;
      bool ok = ((unsigned)gr < (unsigned)H) && ((unsigned)gc < (unsigned)W);
      lin[idx] = ok ? x[(size_t)(ic0 + ic) * P + gr * W + gc] : 0.f;
    }
    __syncthreads();

    for (int ic = 0; ic < ICCH; ++ic) {
      float v[9];
#pragma unroll
      for (int ky = 0; ky < 3; ++ky)
#pragma unroll
        for (int kx = 0; kx < 3; ++kx)
          v[ky * 3 + kx] = lin[ic * LPLANE + (ty + ky) * LROW + (tx + kx)];
      const float* wp = w + (size_t)(ic0 + ic) * 9;  // + oc*64*9 + k
#pragma unroll
      for (int oc = 0; oc < COUT; ++oc) {
#pragma unroll
        for (int k = 0; k < 9; ++k)
          acc[oc] = fmaf(v[k], wp[oc * 64 * 9 + k], acc[oc]);
      }
    }
  }

  int pix = (r0 + ty) * W + (c0 + tx);
#pragma unroll
  for (int oc = 0; oc < COUT; ++oc) {
    float o = acc[oc];
    if (RELU) o = fmaxf(o, 0.f);
    y[(size_t)oc * P + pix] = o;
  }
}

// ---------------- scatter: per-block LDS accumulation -> partials ----------------
__global__ __launch_bounds__(256) void scatter_k(const float* __restrict__ feats,
                                                 const int* __restrict__ pix_rc,
                                                 const int* __restrict__ seg,
                                                 float* __restrict__ partials) {
  __shared__ float ls[NSP * 10];
  __shared__ float lc[NSP];
  int tid = threadIdx.x;
  for (int i = tid; i < NSP * 10; i += 256) ls[i] = 0.f;
  for (int i = tid; i < NSP; i += 256) lc[i] = 0.f;
  __syncthreads();

  constexpr int PER = P / SBLK;  // 4096
  int p0 = blockIdx.x * PER;
  for (int p = p0 + tid; p < p0 + PER; p += 256) {
    int r = pix_rc[2 * p], c = pix_rc[2 * p + 1];
    int s = seg[p];
    int pix = r * W + c;
#pragma unroll
    for (int ch = 0; ch < 10; ++ch)
      atomicAdd(&ls[s * 10 + ch], feats[(size_t)ch * P + pix]);
    atomicAdd(&lc[s], 1.f);
  }
  __syncthreads();

  float* outp = partials + (size_t)blockIdx.x * (NSP * 11);
  for (int i = tid; i < NSP * 10; i += 256) outp[i] = ls[i];
  for (int i = tid; i < NSP; i += 256) outp[NSP * 10 + i] = lc[i];
}

// ---------------- finalize: reduce partials, divide ----------------
__global__ __launch_bounds__(256) void finalize_k(const float* __restrict__ partials,
                                                  float* __restrict__ out) {
  int i = blockIdx.x * 256 + threadIdx.x;  // 10240 outputs
  if (i >= NSP * 10) return;
  int sp = i / 10;
  float s = 0.f, cnt = 0.f;
  for (int bq = 0; bq < SBLK; ++bq) {
    const float* pp = partials + (size_t)bq * (NSP * 11);
    s += pp[i];
    cnt += pp[NSP * 10 + sp];
  }
  out[i] = s / fmaxf(cnt, 1.f);
}

extern "C" void kernel_launch(void* const* d_in, const int* in_sizes, int n_in,
                              void* d_out, int out_size, void* d_ws, size_t ws_size,
                              hipStream_t stream) {
  const float* raw = (const float*)d_in[0];
  const float* w1  = (const float*)d_in[1];
  const float* b1  = (const float*)d_in[2];
  const float* w2  = (const float*)d_in[3];
  const float* b2  = (const float*)d_in[4];
  const float* w3  = (const float*)d_in[5];
  const float* b3  = (const float*)d_in[6];
  const int* pix_rc = (const int*)d_in[7];
  const int* seg    = (const int*)d_in[8];
  float* out = (float*)d_out;

  char* ws = (char*)d_ws;
  float* h1 = (float*)ws;                          // 64*P f32 = 67.1 MB
  float* h2 = (float*)(ws + (size_t)64 * P * 4);   // 64*P f32 = 67.1 MB
  // feats reuses h1's region (h1 dead after conv2); partials right after it.
  float* feats    = (float*)ws;                               // 10*P f32 = 10.5 MB
  float* partials = (float*)(ws + (size_t)10 * P * 4);        // 64*11264 f32 = 2.9 MB

  conv1_k<<<P / 256, 256, 0, stream>>>(raw, w1, b1, h1);
  convN_k<64, true><<<(H / 8) * (W / 32), 256, 0, stream>>>(h1, w2, b2, h2);
  convN_k<10, false><<<(H / 8) * (W / 32), 256, 0, stream>>>(h2, w3, b3, feats);
  scatter_k<<<SBLK, 256, 0, stream>>>(feats, pix_rc, seg, partials);
  finalize_k<<<(NSP * 10 + 255) / 256, 256, 0, stream>>>(partials, out);
}

// Round 2
// 148.313 us; speedup vs baseline: 9.0781x; 9.0781x over previous
//
#include <hip/hip_runtime.h>

typedef __attribute__((ext_vector_type(8))) short short8;
typedef __attribute__((ext_vector_type(4))) float f32x4;

constexpr int H = 512, W = 512;
constexpr int P = H * W;     // 262144
constexpr int NSP = 1024;
constexpr int SBLK = 256;    // scatter partial blocks

__device__ inline unsigned short f2bf(float f) {
  unsigned u = __builtin_bit_cast(unsigned, f);
  unsigned r = (u + 0x7fffu + ((u >> 16) & 1u)) >> 16;  // RNE
  return (unsigned short)r;
}

// ---------------- prep: w2/w3 [oc][ic][tap] f32 -> [oc][tap][ic] bf16 ----------------
__global__ __launch_bounds__(256) void prep_k(const float* __restrict__ w2,
                                              const float* __restrict__ w3,
                                              unsigned short* __restrict__ wt2,
                                              unsigned short* __restrict__ wt3) {
  int i = blockIdx.x * 256 + threadIdx.x;
  if (i < 64 * 576) {
    int oc = i / 576, k = i - oc * 576;
    int tap = k >> 6, ic = k & 63;
    wt2[i] = f2bf(w2[oc * 576 + ic * 9 + tap]);
  } else {
    int j = i - 64 * 576;  // < 16*576 by grid sizing
    int oc = j / 576, k = j - oc * 576;
    int tap = k >> 6, ic = k & 63;
    wt3[j] = (oc < 10) ? f2bf(w3[oc * 576 + ic * 9 + tap]) : (unsigned short)0;
  }
}

// ---------------- conv1: 1 -> 64, ReLU, output NHWC bf16 [pix][64] ----------------
__global__ __launch_bounds__(256) void conv1_k(const float* __restrict__ raw,
                                               const float* __restrict__ w1,
                                               const float* __restrict__ b1,
                                               unsigned short* __restrict__ h1) {
  int pix = blockIdx.x * 256 + threadIdx.x;
  int r = pix >> 9, c = pix & 511;
  float in[9];
#pragma unroll
  for (int ky = 0; ky < 3; ++ky)
#pragma unroll
    for (int kx = 0; kx < 3; ++kx) {
      int rr = r + ky - 1, cc = c + kx - 1;
      bool ok = ((unsigned)rr < (unsigned)H) && ((unsigned)cc < (unsigned)W);
      in[ky * 3 + kx] = ok ? raw[rr * W + cc] : 0.f;
    }
  unsigned out_u[32];
#pragma unroll
  for (int p2 = 0; p2 < 32; ++p2) {
    float a0 = b1[2 * p2], a1 = b1[2 * p2 + 1];
#pragma unroll
    for (int k = 0; k < 9; ++k) {
      a0 = fmaf(in[k], w1[(2 * p2) * 9 + k], a0);
      a1 = fmaf(in[k], w1[(2 * p2 + 1) * 9 + k], a1);
    }
    a0 = fmaxf(a0, 0.f);
    a1 = fmaxf(a1, 0.f);
    out_u[p2] = (unsigned)f2bf(a0) | ((unsigned)f2bf(a1) << 16);
  }
  uint4* dst = reinterpret_cast<uint4*>(h1 + (size_t)pix * 64);
#pragma unroll
  for (int i = 0; i < 8; ++i)
    dst[i] = make_uint4(out_u[4 * i], out_u[4 * i + 1], out_u[4 * i + 2], out_u[4 * i + 3]);
}

// ---------------- convN (MFMA): 64 -> NOCG*16 oc, tile 32x8 pixels ----------------
// xin NHWC bf16 [P][64]; wt [NOCG*16][576] bf16 (k = tap*64+ic); LDS [352 pix][8 slot][8 ic]
// with slot' = slot ^ (pix&7) swizzle (linear LDS dest + pre-swizzled global src).
template <int NOCG, bool RELU, bool NHWC_OUT>
__global__ __launch_bounds__(256) void convN_k(const unsigned short* __restrict__ xin,
                                               const unsigned short* __restrict__ wt,
                                               const float* __restrict__ bias, int cout,
                                               unsigned short* __restrict__ ynhwc,
                                               float* __restrict__ yplanar,
                                               const unsigned short* __restrict__ zeros) {
  __shared__ unsigned short lds[352 * 64];  // 45056 B
  int tid = threadIdx.x;
  int lane = tid & 63, wave = tid >> 6;
  int tilex = blockIdx.x & 15, tiley = blockIdx.x >> 4;
  int c0 = tilex * 32, r0 = tiley * 8;

  // ---- stage whole 64-ic halo tile (34x10 = 340 pixels, padded to 352) ----
#pragma unroll
  for (int it = 0; it < 11; ++it) {
    int cidx = it * 256 + tid;       // cell = (pix, slot')
    int pix = cidx >> 3, slotp = cidx & 7;
    int prow = pix / 34, pcol = pix - prow * 34;
    int gr = r0 + prow - 1, gc = c0 + pcol - 1;
    int slot = slotp ^ (pix & 7);    // inverse swizzle on the SOURCE
    bool ok = (pix < 340) & ((unsigned)gr < 512u) & ((unsigned)gc < 512u);
    const unsigned short* src = ok ? (xin + (((size_t)(gr * 512 + gc)) << 6) + slot * 8) : zeros;
    unsigned short* dstb = &lds[(size_t)(it * 256 + wave * 64) * 8];  // wave-uniform base
    __builtin_amdgcn_global_load_lds((const __attribute__((address_space(1))) void*)src,
                                     (__attribute__((address_space(3))) void*)dstb, 16, 0, 0);
  }
  __syncthreads();

  int q = lane >> 4, n = lane & 15;
  f32x4 acc[NOCG][4];
#pragma unroll
  for (int og = 0; og < NOCG; ++og)
#pragma unroll
    for (int g = 0; g < 4; ++g) acc[og][g] = (f32x4){0.f, 0.f, 0.f, 0.f};

  int plbase[4];
#pragma unroll
  for (int g = 0; g < 4; ++g) {
    int tx0 = 16 * (g & 1);
    int ty0 = wave * 2 + (g >> 1);
    plbase[g] = ty0 * 34 + tx0 + n;
  }
  const char* ldsb = (const char*)lds;

#pragma unroll
  for (int ky = 0; ky < 3; ++ky)
#pragma unroll
    for (int kx = 0; kx < 3; ++kx) {
      int tap = ky * 3 + kx;
#pragma unroll
      for (int kc = 0; kc < 2; ++kc) {
        short8 afrag[NOCG];
#pragma unroll
        for (int og = 0; og < NOCG; ++og) {
          const unsigned short* ap =
              wt + (size_t)(og * 16 + n) * 576 + tap * 64 + kc * 32 + q * 8;
          afrag[og] = *reinterpret_cast<const short8*>(ap);
        }
#pragma unroll
        for (int g = 0; g < 4; ++g) {
          int pl = plbase[g] + ky * 34 + kx;
          int addr = pl * 128 + (((kc * 4 + q) ^ (pl & 7)) * 16);
          short8 bfrag = *reinterpret_cast<const short8*>(ldsb + addr);
#pragma unroll
          for (int og = 0; og < NOCG; ++og)
            acc[og][g] = __builtin_amdgcn_mfma_f32_16x16x32_bf16(afrag[og], bfrag,
                                                                 acc[og][g], 0, 0, 0);
        }
      }
    }

  // ---- epilogue: D lane l, reg r -> oc = og*16 + q*4 + r, pixel col = n ----
#pragma unroll
  for (int og = 0; og < NOCG; ++og) {
    int ocb = og * 16 + q * 4;
    float bb[4];
#pragma unroll
    for (int r2 = 0; r2 < 4; ++r2) {
      int oc = ocb + r2;
      bb[r2] = (oc < cout) ? bias[oc] : 0.f;
    }
#pragma unroll
    for (int g = 0; g < 4; ++g) {
      int pi = wave * 64 + g * 16 + n;
      size_t gpix = (size_t)(r0 + (pi >> 5)) * 512 + (size_t)(c0 + (pi & 31));
      f32x4 v = acc[og][g];
      float o0 = v.x + bb[0], o1 = v.y + bb[1], o2 = v.z + bb[2], o3 = v.w + bb[3];
      if (RELU) {
        o0 = fmaxf(o0, 0.f); o1 = fmaxf(o1, 0.f);
        o2 = fmaxf(o2, 0.f); o3 = fmaxf(o3, 0.f);
      }
      if (NHWC_OUT) {
        unsigned lo = (unsigned)f2bf(o0) | ((unsigned)f2bf(o1) << 16);
        unsigned hi = (unsigned)f2bf(o2) | ((unsigned)f2bf(o3) << 16);
        *reinterpret_cast<uint2*>(ynhwc + gpix * 64 + ocb) = make_uint2(lo, hi);
      } else {
        float ov[4] = {o0, o1, o2, o3};
#pragma unroll
        for (int r2 = 0; r2 < 4; ++r2) {
          int oc = ocb + r2;
          if (oc < 10) yplanar[gpix * 10 + oc] = ov[r2];
        }
      }
    }
  }
}

// ---------------- scatter: LDS accumulate -> per-block partials ----------------
__global__ __launch_bounds__(256) void scatter_k(const float* __restrict__ feats,  // [P][10]
                                                 const int* __restrict__ pix_rc,
                                                 const int* __restrict__ seg,
                                                 float* __restrict__ partials) {
  __shared__ float ls[NSP * 10];
  __shared__ float lc[NSP];
  int tid = threadIdx.x;
  for (int i = tid; i < NSP * 10; i += 256) ls[i] = 0.f;
  for (int i = tid; i < NSP; i += 256) lc[i] = 0.f;
  __syncthreads();

  constexpr int PER = P / SBLK;  // 1024
  int p0 = blockIdx.x * PER;
  for (int p = p0 + tid; p < p0 + PER; p += 256) {
    int r = pix_rc[2 * p], c = pix_rc[2 * p + 1];
    int s = seg[p];
    size_t gpix = (size_t)r * 512 + c;
    const float* fp = feats + gpix * 10;
    float v[10];
#pragma unroll
    for (int h2 = 0; h2 < 5; ++h2) {
      float2 t = *reinterpret_cast<const float2*>(fp + 2 * h2);
      v[2 * h2] = t.x;
      v[2 * h2 + 1] = t.y;
    }
#pragma unroll
    for (int ch = 0; ch < 10; ++ch) atomicAdd(&ls[s * 10 + ch], v[ch]);
    atomicAdd(&lc[s], 1.f);
  }
  __syncthreads();

  float* outp = partials + (size_t)blockIdx.x * (NSP * 11);
  for (int i = tid; i < NSP * 10; i += 256) outp[i] = ls[i];
  for (int i = tid; i < NSP; i += 256) outp[NSP * 10 + i] = lc[i];
}

// ---------------- finalize ----------------
__global__ __launch_bounds__(256) void finalize_k(const float* __restrict__ partials,
                                                  float* __restrict__ out) {
  int i = blockIdx.x * 256 + threadIdx.x;
  if (i >= NSP * 10) return;
  int sp = i / 10;
  float s = 0.f, cnt = 0.f;
  for (int bq = 0; bq < SBLK; ++bq) {
    const float* pp = partials + (size_t)bq * (NSP * 11);
    s += pp[i];
    cnt += pp[NSP * 10 + sp];
  }
  out[i] = s / fmaxf(cnt, 1.f);
}

extern "C" void kernel_launch(void* const* d_in, const int* in_sizes, int n_in,
                              void* d_out, int out_size, void* d_ws, size_t ws_size,
                              hipStream_t stream) {
  const float* raw = (const float*)d_in[0];
  const float* w1  = (const float*)d_in[1];
  const float* b1  = (const float*)d_in[2];
  const float* w2  = (const float*)d_in[3];
  const float* b2  = (const float*)d_in[4];
  const float* w3  = (const float*)d_in[5];
  const float* b3  = (const float*)d_in[6];
  const int* pix_rc = (const int*)d_in[7];
  const int* seg    = (const int*)d_in[8];
  float* out = (float*)d_out;

  char* ws = (char*)d_ws;
  unsigned short* h1   = (unsigned short*)(ws + 0);          // [P][64] bf16, 33.55 MB
  unsigned short* h2   = (unsigned short*)(ws + 33554432);   // [P][64] bf16, 33.55 MB
  float* feats         = (float*)(ws + 67108864);            // [P][10] f32, 10.49 MB
  unsigned short* wt2  = (unsigned short*)(ws + 77594624);   // [64][576] bf16
  unsigned short* wt3  = (unsigned short*)(ws + 77668352);   // [16][576] bf16
  unsigned short* zeros = (unsigned short*)(ws + 77686784);  // 256 B zero stub
  float* partials      = (float*)(ws + 77687040);            // 256 * 11264 f32

  hipMemsetAsync(zeros, 0, 256, stream);
  prep_k<<<180, 256, 0, stream>>>(w2, w3, wt2, wt3);
  conv1_k<<<P / 256, 256, 0, stream>>>(raw, w1, b1, h1);
  convN_k<4, true, true><<<1024, 256, 0, stream>>>(h1, wt2, b2, 64, h2, nullptr, zeros);
  convN_k<1, false, false><<<1024, 256, 0, stream>>>(h2, wt3, b3, 10, nullptr, feats, zeros);
  scatter_k<<<SBLK, 256, 0, stream>>>(feats, pix_rc, seg, partials);
  finalize_k<<<40, 256, 0, stream>>>(partials, out);
}

// Round 3
// 124.974 us; speedup vs baseline: 10.7734x; 1.1867x over previous
//
#include <hip/hip_runtime.h>

typedef __attribute__((ext_vector_type(8))) short short8;
typedef __attribute__((ext_vector_type(4))) float f32x4;

constexpr int H = 512, W = 512;
constexpr int P = H * W;     // 262144
constexpr int NSP = 1024;
constexpr int SBLK = 256;    // scatter partial blocks

__device__ inline unsigned short f2bf(float f) {
  unsigned u = __builtin_bit_cast(unsigned, f);
  unsigned r = (u + 0x7fffu + ((u >> 16) & 1u)) >> 16;  // RNE
  return (unsigned short)r;
}

// ---------------- prep: weights -> staged-order bf16 with baked-in swizzle ----------------
// Chunk k (= tap*2 + kc) is WCS 16B-cells; cell t = (row r = t>>2, slot' = t&3);
// stored ic-slot s = slot' ^ (r&3)  => linear DMA write + swizzled ds_read are conflict-free.
__global__ __launch_bounds__(256) void prep_k(const float* __restrict__ w2,
                                              const float* __restrict__ w3,
                                              unsigned short* __restrict__ wt2s,
                                              unsigned short* __restrict__ wt3s) {
  int i = blockIdx.x * 256 + threadIdx.x;
  if (i < 36864) {                     // conv2: 18 chunks x 2048 shorts (64 oc rows)
    int k = i >> 11;
    int t = (i >> 3) & 255;
    int e = i & 7;
    int r = t >> 2, sp = t & 3, s = sp ^ (r & 3);
    int tap = k >> 1, ic = (k & 1) * 32 + s * 8 + e;
    wt2s[i] = f2bf(w2[r * 576 + ic * 9 + tap]);
  } else {                             // conv3: 18 chunks x 512 shorts (16 oc rows, 10 real)
    int j = i - 36864;                 // < 9216 by grid sizing (180 blocks)
    int k = j >> 9;
    int t = (j >> 3) & 63;
    int e = j & 7;
    int r = t >> 2, sp = t & 3, s = sp ^ (r & 3);
    int tap = k >> 1, ic = (k & 1) * 32 + s * 8 + e;
    wt3s[j] = (r < 10) ? f2bf(w3[r * 576 + ic * 9 + tap]) : (unsigned short)0;
  }
}

// ---------------- conv1: 1 -> 64, ReLU, output NHWC bf16 [pix][64] ----------------
__global__ __launch_bounds__(256) void conv1_k(const float* __restrict__ raw,
                                               const float* __restrict__ w1,
                                               const float* __restrict__ b1,
                                               unsigned short* __restrict__ h1) {
  int pix = blockIdx.x * 256 + threadIdx.x;
  int r = pix >> 9, c = pix & 511;
  float in[9];
#pragma unroll
  for (int ky = 0; ky < 3; ++ky)
#pragma unroll
    for (int kx = 0; kx < 3; ++kx) {
      int rr = r + ky - 1, cc = c + kx - 1;
      bool ok = ((unsigned)rr < (unsigned)H) && ((unsigned)cc < (unsigned)W);
      in[ky * 3 + kx] = ok ? raw[rr * W + cc] : 0.f;
    }
  unsigned out_u[32];
#pragma unroll
  for (int p2 = 0; p2 < 32; ++p2) {
    float a0 = b1[2 * p2], a1 = b1[2 * p2 + 1];
#pragma unroll
    for (int k = 0; k < 9; ++k) {
      a0 = fmaf(in[k], w1[(2 * p2) * 9 + k], a0);
      a1 = fmaf(in[k], w1[(2 * p2 + 1) * 9 + k], a1);
    }
    a0 = fmaxf(a0, 0.f);
    a1 = fmaxf(a1, 0.f);
    out_u[p2] = (unsigned)f2bf(a0) | ((unsigned)f2bf(a1) << 16);
  }
  uint4* dst = reinterpret_cast<uint4*>(h1 + (size_t)pix * 64);
#pragma unroll
  for (int i = 0; i < 8; ++i)
    dst[i] = make_uint4(out_u[4 * i], out_u[4 * i + 1], out_u[4 * i + 2], out_u[4 * i + 3]);
}

// ---------------- convN (MFMA, weights pipelined through LDS) ----------------
// xin NHWC bf16 [P][64]; wts staged-order (see prep_k); acts LDS [352 pix][8 slot][8 ic]
// with slot' = slot ^ (pix&7); weight ring wbuf[3] with depth-2 counted-vmcnt pipeline.
template <int NOCG, bool RELU, bool NHWC_OUT>
__global__ __launch_bounds__(256) void convN_k(const unsigned short* __restrict__ xin,
                                               const unsigned short* __restrict__ wts,
                                               const float* __restrict__ bias, int cout,
                                               unsigned short* __restrict__ ynhwc,
                                               float* __restrict__ yplanar,
                                               const unsigned short* __restrict__ zeros) {
  constexpr int WCS = NOCG * 512;                      // chunk size in shorts
  __shared__ __align__(16) unsigned short acts[352 * 64];  // 45056 B
  __shared__ __align__(16) unsigned short wbuf[3 * WCS];   // 12288 B (conv2) / 3072 B (conv3)
  int tid = threadIdx.x;
  int lane = tid & 63, wave = tid >> 6;
  int tilex = blockIdx.x & 15, tiley = blockIdx.x >> 4;
  int c0 = tilex * 32, r0 = tiley * 8;

  // ---- stage whole 64-ic halo tile (34x10 = 340 pixels, padded to 352) ----
#pragma unroll
  for (int it = 0; it < 11; ++it) {
    int cidx = it * 256 + tid;       // cell = (pix, slot')
    int pix = cidx >> 3, slotp = cidx & 7;
    int prow = pix / 34, pcol = pix - prow * 34;
    int gr = r0 + prow - 1, gc = c0 + pcol - 1;
    int slot = slotp ^ (pix & 7);    // inverse swizzle on the SOURCE
    bool ok = (pix < 340) & ((unsigned)gr < 512u) & ((unsigned)gc < 512u);
    const unsigned short* src = ok ? (xin + (((size_t)(gr * 512 + gc)) << 6) + slot * 8) : zeros;
    unsigned short* dstb = &acts[(size_t)(it * 256 + wave * 64) * 8];  // wave-uniform base
    __builtin_amdgcn_global_load_lds((const __attribute__((address_space(1))) void*)src,
                                     (__attribute__((address_space(3))) void*)dstb, 16, 0, 0);
  }
  // ---- prologue weight chunks 0,1 ----
#pragma unroll
  for (int k0 = 0; k0 < 2; ++k0) {
    if (tid < NOCG * 64) {
      const unsigned short* src = wts + (size_t)k0 * WCS + tid * 8;
      unsigned short* dstb = wbuf + k0 * WCS + wave * 512;
      __builtin_amdgcn_global_load_lds((const __attribute__((address_space(1))) void*)src,
                                       (__attribute__((address_space(3))) void*)dstb, 16, 0, 0);
    }
  }
  __syncthreads();  // full drain (vmcnt(0)) — pipeline starts clean

  int q = lane >> 4, n = lane & 15;
  f32x4 acc[NOCG][4];
#pragma unroll
  for (int og = 0; og < NOCG; ++og)
#pragma unroll
    for (int g = 0; g < 4; ++g) acc[og][g] = (f32x4){0.f, 0.f, 0.f, 0.f};

  int plbase[4];
#pragma unroll
  for (int g = 0; g < 4; ++g) {
    int tx0 = 16 * (g & 1);
    int ty0 = wave * 2 + (g >> 1);
    plbase[g] = ty0 * 34 + tx0 + n;
  }
  const char* actb = (const char*)acts;

  // ---- 18-step main loop: counted vmcnt, raw barrier, depth-2 weight prefetch ----
#pragma unroll
  for (int k = 0; k < 18; ++k) {
    asm volatile("s_waitcnt vmcnt(1)" ::: "memory");   // chunk k landed (in-order counter)
    __builtin_amdgcn_sched_barrier(0);
    __builtin_amdgcn_s_barrier();                      // all waves see it; NO drain
    __builtin_amdgcn_sched_barrier(0);
    if (k + 2 < 18) {                                  // issue AFTER barrier: ring slot
      if (tid < NOCG * 64) {                           // (k+2)%3 readers finished step k-1
        const unsigned short* src = wts + (size_t)(k + 2) * WCS + tid * 8;
        unsigned short* dstb = wbuf + ((k + 2) % 3) * WCS + wave * 512;
        __builtin_amdgcn_global_load_lds((const __attribute__((address_space(1))) void*)src,
                                         (__attribute__((address_space(3))) void*)dstb, 16, 0, 0);
      }
    }
    const int tap = k >> 1, kc = k & 1;
    const int kyy = tap / 3, kxx = tap - kyy * 3;
    const char* wb = (const char*)(wbuf + (k % 3) * WCS);
    short8 af[NOCG];
#pragma unroll
    for (int og = 0; og < NOCG; ++og) {
      int r = og * 16 + n;
      af[og] = *reinterpret_cast<const short8*>(wb + r * 64 + ((q ^ (r & 3)) * 16));
    }
#pragma unroll
    for (int g = 0; g < 4; ++g) {
      int pl = plbase[g] + kyy * 34 + kxx;
      int addr = pl * 128 + (((kc * 4 + q) ^ (pl & 7)) * 16);
      short8 bf = *reinterpret_cast<const short8*>(actb + addr);
#pragma unroll
      for (int og = 0; og < NOCG; ++og)
        acc[og][g] = __builtin_amdgcn_mfma_f32_16x16x32_bf16(af[og], bf, acc[og][g], 0, 0, 0);
    }
  }

  // ---- epilogue: D lane l, reg r -> oc = og*16 + q*4 + r, pixel col = n ----
#pragma unroll
  for (int og = 0; og < NOCG; ++og) {
    int ocb = og * 16 + q * 4;
    float bb[4];
#pragma unroll
    for (int r2 = 0; r2 < 4; ++r2) {
      int oc = ocb + r2;
      bb[r2] = (oc < cout) ? bias[oc] : 0.f;
    }
#pragma unroll
    for (int g = 0; g < 4; ++g) {
      int pi = wave * 64 + g * 16 + n;
      size_t gpix = (size_t)(r0 + (pi >> 5)) * 512 + (size_t)(c0 + (pi & 31));
      f32x4 v = acc[og][g];
      float o0 = v.x + bb[0], o1 = v.y + bb[1], o2 = v.z + bb[2], o3 = v.w + bb[3];
      if (RELU) {
        o0 = fmaxf(o0, 0.f); o1 = fmaxf(o1, 0.f);
        o2 = fmaxf(o2, 0.f); o3 = fmaxf(o3, 0.f);
      }
      if (NHWC_OUT) {
        unsigned lo = (unsigned)f2bf(o0) | ((unsigned)f2bf(o1) << 16);
        unsigned hi = (unsigned)f2bf(o2) | ((unsigned)f2bf(o3) << 16);
        *reinterpret_cast<uint2*>(ynhwc + gpix * 64 + ocb) = make_uint2(lo, hi);
      } else {
        float ov[4] = {o0, o1, o2, o3};
#pragma unroll
        for (int r2 = 0; r2 < 4; ++r2) {
          int oc = ocb + r2;
          if (oc < 10) yplanar[gpix * 10 + oc] = ov[r2];
        }
      }
    }
  }
}

// ---------------- scatter: LDS accumulate -> per-block partials ----------------
__global__ __launch_bounds__(256) void scatter_k(const float* __restrict__ feats,  // [P][10]
                                                 const int* __restrict__ pix_rc,
                                                 const int* __restrict__ seg,
                                                 float* __restrict__ partials) {
  __shared__ float ls[NSP * 10];
  __shared__ float lc[NSP];
  int tid = threadIdx.x;
  for (int i = tid; i < NSP * 10; i += 256) ls[i] = 0.f;
  for (int i = tid; i < NSP; i += 256) lc[i] = 0.f;
  __syncthreads();

  constexpr int PER = P / SBLK;  // 1024
  int p0 = blockIdx.x * PER;
  for (int p = p0 + tid; p < p0 + PER; p += 256) {
    int r = pix_rc[2 * p], c = pix_rc[2 * p + 1];
    int s = seg[p];
    size_t gpix = (size_t)r * 512 + c;
    const float* fp = feats + gpix * 10;
    float v[10];
#pragma unroll
    for (int h2 = 0; h2 < 5; ++h2) {
      float2 t = *reinterpret_cast<const float2*>(fp + 2 * h2);
      v[2 * h2] = t.x;
      v[2 * h2 + 1] = t.y;
    }
#pragma unroll
    for (int ch = 0; ch < 10; ++ch) atomicAdd(&ls[s * 10 + ch], v[ch]);
    atomicAdd(&lc[s], 1.f);
  }
  __syncthreads();

  float* outp = partials + (size_t)blockIdx.x * (NSP * 11);
  for (int i = tid; i < NSP * 10; i += 256) outp[i] = ls[i];
  for (int i = tid; i < NSP; i += 256) outp[NSP * 10 + i] = lc[i];
}

// ---------------- finalize ----------------
__global__ __launch_bounds__(256) void finalize_k(const float* __restrict__ partials,
                                                  float* __restrict__ out) {
  int i = blockIdx.x * 256 + threadIdx.x;
  if (i >= NSP * 10) return;
  int sp = i / 10;
  float s = 0.f, cnt = 0.f;
  for (int bq = 0; bq < SBLK; ++bq) {
    const float* pp = partials + (size_t)bq * (NSP * 11);
    s += pp[i];
    cnt += pp[NSP * 10 + sp];
  }
  out[i] = s / fmaxf(cnt, 1.f);
}

extern "C" void kernel_launch(void* const* d_in, const int* in_sizes, int n_in,
                              void* d_out, int out_size, void* d_ws, size_t ws_size,
                              hipStream_t stream) {
  const float* raw = (const float*)d_in[0];
  const float* w1  = (const float*)d_in[1];
  const float* b1  = (const float*)d_in[2];
  const float* w2  = (const float*)d_in[3];
  const float* b2  = (const float*)d_in[4];
  const float* w3  = (const float*)d_in[5];
  const float* b3  = (const float*)d_in[6];
  const int* pix_rc = (const int*)d_in[7];
  const int* seg    = (const int*)d_in[8];
  float* out = (float*)d_out;

  char* ws = (char*)d_ws;
  unsigned short* h1   = (unsigned short*)(ws + 0);          // [P][64] bf16, 33.55 MB
  unsigned short* h2   = (unsigned short*)(ws + 33554432);   // [P][64] bf16, 33.55 MB
  float* feats         = (float*)(ws + 67108864);            // [P][10] f32, 10.49 MB
  unsigned short* wt2s = (unsigned short*)(ws + 77594624);   // 18*2048 shorts = 73728 B
  unsigned short* wt3s = (unsigned short*)(ws + 77668352);   // 18*512 shorts = 18432 B
  unsigned short* zeros = (unsigned short*)(ws + 77686784);  // 256 B zero stub
  float* partials      = (float*)(ws + 77687040);            // 256 * 11264 f32

  hipMemsetAsync(zeros, 0, 256, stream);
  prep_k<<<180, 256, 0, stream>>>(w2, w3, wt2s, wt3s);
  conv1_k<<<P / 256, 256, 0, stream>>>(raw, w1, b1, h1);
  convN_k<4, true, true><<<1024, 256, 0, stream>>>(h1, wt2s, b2, 64, h2, nullptr, zeros);
  convN_k<1, false, false><<<1024, 256, 0, stream>>>(h2, wt3s, b3, 10, nullptr, feats, zeros);
  scatter_k<<<SBLK, 256, 0, stream>>>(feats, pix_rc, seg, partials);
  finalize_k<<<40, 256, 0, stream>>>(partials, out);
}

// Round 4
// 116.800 us; speedup vs baseline: 11.5273x; 1.0700x over previous
//
#include <hip/hip_runtime.h>

typedef __attribute__((ext_vector_type(8))) short short8;
typedef __attribute__((ext_vector_type(4))) float f32x4;

constexpr int H = 512, W = 512;
constexpr int P = H * W;     // 262144
constexpr int NSP = 1024;
constexpr int SBLK = 256;    // scatter partial blocks

__device__ inline unsigned short f2bf(float f) {
  unsigned u = __builtin_bit_cast(unsigned, f);
  unsigned r = (u + 0x7fffu + ((u >> 16) & 1u)) >> 16;  // RNE
  return (unsigned short)r;
}

// ---------------- prep: weights -> staged-order bf16 with baked-in swizzle ----------------
// Chunk k (= tap*2 + kc) of WCS 16B-cells; cell t = (row r = t>>2, slot' = t&3);
// stored ic-slot s = slot' ^ (r&3)  => linear DMA write + swizzled ds_read are conflict-free.
__global__ __launch_bounds__(256) void prep_k(const float* __restrict__ w2,
                                              const float* __restrict__ w3,
                                              unsigned short* __restrict__ wt2s,
                                              unsigned short* __restrict__ wt3s,
                                              unsigned short* __restrict__ zeros) {
  if (blockIdx.x == 0 && threadIdx.x < 128) zeros[threadIdx.x] = 0;  // 256-B zero stub
  int i = blockIdx.x * 256 + threadIdx.x;
  if (i < 36864) {                     // conv2: 18 chunks x 2048 shorts (64 oc rows)
    int k = i >> 11;
    int t = (i >> 3) & 255;
    int e = i & 7;
    int r = t >> 2, sp = t & 3, s = sp ^ (r & 3);
    int tap = k >> 1, ic = (k & 1) * 32 + s * 8 + e;
    wt2s[i] = f2bf(w2[r * 576 + ic * 9 + tap]);
  } else {                             // conv3: 18 chunks x 512 shorts (16 oc rows, 10 real)
    int j = i - 36864;                 // < 9216 by grid sizing (180 blocks)
    int k = j >> 9;
    int t = (j >> 3) & 63;
    int e = j & 7;
    int r = t >> 2, sp = t & 3, s = sp ^ (r & 3);
    int tap = k >> 1, ic = (k & 1) * 32 + s * 8 + e;
    wt3s[j] = (r < 10) ? f2bf(w3[r * 576 + ic * 9 + tap]) : (unsigned short)0;
  }
}

// ---------------- conv1: 1 -> 64, ReLU, output NHWC bf16 [pix][64] ----------------
__global__ __launch_bounds__(256) void conv1_k(const float* __restrict__ raw,
                                               const float* __restrict__ w1,
                                               const float* __restrict__ b1,
                                               unsigned short* __restrict__ h1) {
  int pix = blockIdx.x * 256 + threadIdx.x;
  int r = pix >> 9, c = pix & 511;
  float in[9];
#pragma unroll
  for (int ky = 0; ky < 3; ++ky)
#pragma unroll
    for (int kx = 0; kx < 3; ++kx) {
      int rr = r + ky - 1, cc = c + kx - 1;
      bool ok = ((unsigned)rr < (unsigned)H) && ((unsigned)cc < (unsigned)W);
      in[ky * 3 + kx] = ok ? raw[rr * W + cc] : 0.f;
    }
  unsigned out_u[32];
#pragma unroll
  for (int p2 = 0; p2 < 32; ++p2) {
    float a0 = b1[2 * p2], a1 = b1[2 * p2 + 1];
#pragma unroll
    for (int k = 0; k < 9; ++k) {
      a0 = fmaf(in[k], w1[(2 * p2) * 9 + k], a0);
      a1 = fmaf(in[k], w1[(2 * p2 + 1) * 9 + k], a1);
    }
    a0 = fmaxf(a0, 0.f);
    a1 = fmaxf(a1, 0.f);
    out_u[p2] = (unsigned)f2bf(a0) | ((unsigned)f2bf(a1) << 16);
  }
  uint4* dst = reinterpret_cast<uint4*>(h1 + (size_t)pix * 64);
#pragma unroll
  for (int i = 0; i < 8; ++i)
    dst[i] = make_uint4(out_u[4 * i], out_u[4 * i + 1], out_u[4 * i + 2], out_u[4 * i + 3]);
}

// Shared acts staging: 344-pixel halo tile (340 used), 43 wave-issues of 1 KiB.
// LDS layout: [pix][8 slot'][8 ic] with slot' = slot ^ (pix&7).
__device__ inline void stage_acts(const unsigned short* __restrict__ xin,
                                  const unsigned short* __restrict__ zeros,
                                  unsigned short* acts, int r0, int c0,
                                  int wave, int lane) {
  for (int wi = wave; wi < 43; wi += 4) {
    int cidx = wi * 64 + lane;
    int pix = cidx >> 3, slotp = cidx & 7;
    int prow = pix / 34, pcol = pix - prow * 34;
    int gr = r0 + prow - 1, gc = c0 + pcol - 1;
    int slot = slotp ^ (pix & 7);
    bool ok = (pix < 340) & ((unsigned)gr < 512u) & ((unsigned)gc < 512u);
    const unsigned short* src = ok ? (xin + (((size_t)(gr * 512 + gc)) << 6) + slot * 8) : zeros;
    unsigned short* dstb = &acts[wi * 512];  // wave-uniform base
    __builtin_amdgcn_global_load_lds((const __attribute__((address_space(1))) void*)src,
                                     (__attribute__((address_space(3))) void*)dstb, 16, 0, 0);
  }
}

// ---------------- conv2 (MFMA): 64 -> 64, ReLU, NHWC out; weight ring pipeline ----------------
__global__ __launch_bounds__(256) void conv2_k(const unsigned short* __restrict__ xin,
                                               const unsigned short* __restrict__ wts,
                                               const float* __restrict__ bias,
                                               unsigned short* __restrict__ ynhwc,
                                               const unsigned short* __restrict__ zeros) {
  constexpr int WCS = 2048;                                // chunk shorts (4 KiB)
  __shared__ __align__(16) unsigned short acts[344 * 64];  // 44032 B
  __shared__ __align__(16) unsigned short wbuf[3 * WCS];   // 12288 B
  int tid = threadIdx.x;
  int lane = tid & 63, wave = tid >> 6;
  int tilex = blockIdx.x & 15, tiley = blockIdx.x >> 4;
  int c0 = tilex * 32, r0 = tiley * 8;

  stage_acts(xin, zeros, acts, r0, c0, wave, lane);
#pragma unroll
  for (int k0 = 0; k0 < 2; ++k0) {                         // prologue chunks 0,1
    const unsigned short* src = wts + (size_t)k0 * WCS + tid * 8;
    unsigned short* dstb = wbuf + k0 * WCS + wave * 512;
    __builtin_amdgcn_global_load_lds((const __attribute__((address_space(1))) void*)src,
                                     (__attribute__((address_space(3))) void*)dstb, 16, 0, 0);
  }
  __syncthreads();  // full drain — pipeline starts clean

  int q = lane >> 4, n = lane & 15;
  f32x4 acc[4][4];
#pragma unroll
  for (int og = 0; og < 4; ++og)
#pragma unroll
    for (int g = 0; g < 4; ++g) acc[og][g] = (f32x4){0.f, 0.f, 0.f, 0.f};

  int plbase[4];
#pragma unroll
  for (int g = 0; g < 4; ++g)
    plbase[g] = (wave * 2 + (g >> 1)) * 34 + 16 * (g & 1) + n;
  const char* actb = (const char*)acts;

#pragma unroll
  for (int k = 0; k < 18; ++k) {
    asm volatile("s_waitcnt vmcnt(1)" ::: "memory");   // own chunk-k part landed
    __builtin_amdgcn_sched_barrier(0);
    __builtin_amdgcn_s_barrier();                      // all parts landed; NO drain
    __builtin_amdgcn_sched_barrier(0);
    if (k + 2 < 18) {                                  // slot (k+2)%3 free: read at k-1
      const unsigned short* src = wts + (size_t)(k + 2) * WCS + tid * 8;
      unsigned short* dstb = wbuf + ((k + 2) % 3) * WCS + wave * 512;
      __builtin_amdgcn_global_load_lds((const __attribute__((address_space(1))) void*)src,
                                       (__attribute__((address_space(3))) void*)dstb, 16, 0, 0);
    }
    const int tap = k >> 1, kc = k & 1;
    const int kyy = tap / 3, kxx = tap - kyy * 3;
    const char* wb = (const char*)(wbuf + (k % 3) * WCS);
    short8 af[4];
#pragma unroll
    for (int og = 0; og < 4; ++og) {
      int r = og * 16 + n;
      af[og] = *reinterpret_cast<const short8*>(wb + r * 64 + ((q ^ (r & 3)) * 16));
    }
#pragma unroll
    for (int g = 0; g < 4; ++g) {
      int pl = plbase[g] + kyy * 34 + kxx;
      int addr = pl * 128 + (((kc * 4 + q) ^ (pl & 7)) * 16);
      short8 bf = *reinterpret_cast<const short8*>(actb + addr);
#pragma unroll
      for (int og = 0; og < 4; ++og)
        acc[og][g] = __builtin_amdgcn_mfma_f32_16x16x32_bf16(af[og], bf, acc[og][g], 0, 0, 0);
    }
  }

  // ---- epilogue: acc -> LDS (swizzled NHWC tile) -> coalesced 16B stores ----
  __syncthreads();  // acts reads done; safe to reuse as output staging
  char* ob = (char*)acts;
#pragma unroll
  for (int og = 0; og < 4; ++og) {
    float b0 = bias[og * 16 + q * 4 + 0], b1 = bias[og * 16 + q * 4 + 1];
    float b2 = bias[og * 16 + q * 4 + 2], b3 = bias[og * 16 + q * 4 + 3];
#pragma unroll
    for (int g = 0; g < 4; ++g) {
      int pl = wave * 64 + g * 16 + n;
      f32x4 v = acc[og][g];
      float o0 = fmaxf(v.x + b0, 0.f), o1 = fmaxf(v.y + b1, 0.f);
      float o2 = fmaxf(v.z + b2, 0.f), o3 = fmaxf(v.w + b3, 0.f);
      unsigned lo = (unsigned)f2bf(o0) | ((unsigned)f2bf(o1) << 16);
      unsigned hi = (unsigned)f2bf(o2) | ((unsigned)f2bf(o3) << 16);
      int lslot = og * 2 + (q >> 1);                   // logical 16B slot
      int wa = pl * 128 + (((lslot ^ (pl & 7)) << 4)) + ((q & 1) << 3);
      *reinterpret_cast<uint2*>(ob + wa) = make_uint2(lo, hi);
    }
  }
  __syncthreads();
  char* yb = (char*)ynhwc;
#pragma unroll
  for (int it = 0; it < 8; ++it) {
    int c = it * 256 + tid;                            // 2048 16-B chunks
    int pl = c >> 3, slot = c & 7;
    uint4 v = *reinterpret_cast<const uint4*>(ob + pl * 128 + ((slot ^ (pl & 7)) << 4));
    size_t gb = (((size_t)(r0 + (pl >> 5)) * 512) + c0 + (pl & 31)) * 128 + slot * 16;
    *reinterpret_cast<uint4*>(yb + gb) = v;
  }
}

// ---------------- conv3 (MFMA): 64 -> 10, planar f32 out; weights fully LDS-resident ----------------
__global__ __launch_bounds__(256) void conv3_k(const unsigned short* __restrict__ xin,
                                               const unsigned short* __restrict__ wts,
                                               const float* __restrict__ bias,
                                               float* __restrict__ feats,
                                               const unsigned short* __restrict__ zeros) {
  __shared__ __align__(16) unsigned short acts[344 * 64];  // 44032 B
  __shared__ __align__(16) unsigned short wl[9216];        // 18432 B (18 chunks x 1 KiB)
  int tid = threadIdx.x;
  int lane = tid & 63, wave = tid >> 6;
  int tilex = blockIdx.x & 15, tiley = blockIdx.x >> 4;
  int c0 = tilex * 32, r0 = tiley * 8;

  stage_acts(xin, zeros, acts, r0, c0, wave, lane);
  for (int wi = wave; wi < 18; wi += 4) {                  // all 18 KB of weights, once
    const unsigned short* src = wts + (size_t)wi * 512 + lane * 8;
    unsigned short* dstb = &wl[wi * 512];
    __builtin_amdgcn_global_load_lds((const __attribute__((address_space(1))) void*)src,
                                     (__attribute__((address_space(3))) void*)dstb, 16, 0, 0);
  }
  __syncthreads();

  int q = lane >> 4, n = lane & 15;
  f32x4 acc[4];
#pragma unroll
  for (int g = 0; g < 4; ++g) acc[g] = (f32x4){0.f, 0.f, 0.f, 0.f};
  int plbase[4];
#pragma unroll
  for (int g = 0; g < 4; ++g)
    plbase[g] = (wave * 2 + (g >> 1)) * 34 + 16 * (g & 1) + n;
  const char* actb = (const char*)acts;
  const char* wb0 = (const char*)wl;

#pragma unroll
  for (int k = 0; k < 18; ++k) {                           // no barriers, no waitcnts
    const int tap = k >> 1, kc = k & 1;
    const int kyy = tap / 3, kxx = tap - kyy * 3;
    short8 af = *reinterpret_cast<const short8*>(wb0 + k * 1024 + n * 64 + ((q ^ (n & 3)) * 16));
#pragma unroll
    for (int g = 0; g < 4; ++g) {
      int pl = plbase[g] + kyy * 34 + kxx;
      int addr = pl * 128 + (((kc * 4 + q) ^ (pl & 7)) * 16);
      short8 bf = *reinterpret_cast<const short8*>(actb + addr);
      acc[g] = __builtin_amdgcn_mfma_f32_16x16x32_bf16(af, bf, acc[g], 0, 0, 0);
    }
  }

  // ---- epilogue: acc -> LDS (stride-48 rows) -> coalesced 8B copies ----
  __syncthreads();
  char* ob = (char*)acts;
  float bb[4];
#pragma unroll
  for (int r2 = 0; r2 < 4; ++r2) {
    int oc = q * 4 + r2;
    bb[r2] = (oc < 10) ? bias[oc] : 0.f;
  }
#pragma unroll
  for (int g = 0; g < 4; ++g) {
    int pl = wave * 64 + g * 16 + n;
    f32x4 v = acc[g];
    float o0 = v.x + bb[0], o1 = v.y + bb[1], o2 = v.z + bb[2], o3 = v.w + bb[3];
    if (q < 2) {
      *reinterpret_cast<f32x4*>(ob + pl * 48 + q * 16) = (f32x4){o0, o1, o2, o3};
    } else if (q == 2) {
      *reinterpret_cast<float2*>(ob + pl * 48 + 32) = make_float2(o0, o1);
    }
  }
  __syncthreads();
  char* fb = (char*)feats;
#pragma unroll
  for (int it = 0; it < 5; ++it) {
    int c = it * 256 + tid;                            // 1280 8-B chunks (8 rows x 1280 B)
    int row = c / 160, ib = (c - row * 160) * 8;
    int px = ib / 40, off = ib - px * 40;
    uint2 v = *reinterpret_cast<const uint2*>(ob + (row * 32 + px) * 48 + off);
    size_t gb = (((size_t)(r0 + row) * 512) + c0) * 40 + (size_t)ib;
    *reinterpret_cast<uint2*>(fb + gb) = v;
  }
}

// ---------------- scatter: LDS accumulate -> per-block partials ----------------
__global__ __launch_bounds__(256) void scatter_k(const float* __restrict__ feats,  // [P][10]
                                                 const int* __restrict__ pix_rc,
                                                 const int* __restrict__ seg,
                                                 float* __restrict__ partials) {
  __shared__ float ls[NSP * 10];
  __shared__ float lc[NSP];
  int tid = threadIdx.x;
  for (int i = tid; i < NSP * 10; i += 256) ls[i] = 0.f;
  for (int i = tid; i < NSP; i += 256) lc[i] = 0.f;
  __syncthreads();

  constexpr int PER = P / SBLK;  // 1024
  int p0 = blockIdx.x * PER;
  for (int p = p0 + tid; p < p0 + PER; p += 256) {
    int r = pix_rc[2 * p], c = pix_rc[2 * p + 1];
    int s = seg[p];
    size_t gpix = (size_t)r * 512 + c;
    const float* fp = feats + gpix * 10;
    float v[10];
#pragma unroll
    for (int h2 = 0; h2 < 5; ++h2) {
      float2 t = *reinterpret_cast<const float2*>(fp + 2 * h2);
      v[2 * h2] = t.x;
      v[2 * h2 + 1] = t.y;
    }
#pragma unroll
    for (int ch = 0; ch < 10; ++ch) atomicAdd(&ls[s * 10 + ch], v[ch]);
    atomicAdd(&lc[s], 1.f);
  }
  __syncthreads();

  float* outp = partials + (size_t)blockIdx.x * (NSP * 11);
  for (int i = tid; i < NSP * 10; i += 256) outp[i] = ls[i];
  for (int i = tid; i < NSP; i += 256) outp[NSP * 10 + i] = lc[i];
}

// ---------------- finalize ----------------
__global__ __launch_bounds__(256) void finalize_k(const float* __restrict__ partials,
                                                  float* __restrict__ out) {
  int i = blockIdx.x * 256 + threadIdx.x;
  if (i >= NSP * 10) return;
  int sp = i / 10;
  float s = 0.f, cnt = 0.f;
  for (int bq = 0; bq < SBLK; ++bq) {
    const float* pp = partials + (size_t)bq * (NSP * 11);
    s += pp[i];
    cnt += pp[NSP * 10 + sp];
  }
  out[i] = s / fmaxf(cnt, 1.f);
}

extern "C" void kernel_launch(void* const* d_in, const int* in_sizes, int n_in,
                              void* d_out, int out_size, void* d_ws, size_t ws_size,
                              hipStream_t stream) {
  const float* raw = (const float*)d_in[0];
  const float* w1  = (const float*)d_in[1];
  const float* b1  = (const float*)d_in[2];
  const float* w2  = (const float*)d_in[3];
  const float* b2  = (const float*)d_in[4];
  const float* w3  = (const float*)d_in[5];
  const float* b3  = (const float*)d_in[6];
  const int* pix_rc = (const int*)d_in[7];
  const int* seg    = (const int*)d_in[8];
  float* out = (float*)d_out;

  char* ws = (char*)d_ws;
  unsigned short* h1   = (unsigned short*)(ws + 0);          // [P][64] bf16, 33.55 MB
  unsigned short* h2   = (unsigned short*)(ws + 33554432);   // [P][64] bf16, 33.55 MB
  float* feats         = (float*)(ws + 67108864);            // [P][10] f32, 10.49 MB
  unsigned short* wt2s = (unsigned short*)(ws + 77594624);   // 36864 shorts = 73728 B
  unsigned short* wt3s = (unsigned short*)(ws + 77668352);   // 9216 shorts = 18432 B
  unsigned short* zeros = (unsigned short*)(ws + 77686784);  // 256 B zero stub
  float* partials      = (float*)(ws + 77687040);            // 256 * 11264 f32

  prep_k<<<180, 256, 0, stream>>>(w2, w3, wt2s, wt3s, zeros);
  conv1_k<<<P / 256, 256, 0, stream>>>(raw, w1, b1, h1);
  conv2_k<<<1024, 256, 0, stream>>>(h1, wt2s, b2, h2, zeros);
  conv3_k<<<1024, 256, 0, stream>>>(h2, wt3s, b3, feats, zeros);
  scatter_k<<<SBLK, 256, 0, stream>>>(feats, pix_rc, seg, partials);
  finalize_k<<<40, 256, 0, stream>>>(partials, out);
}

// Round 5
// 111.058 us; speedup vs baseline: 12.1234x; 1.0517x over previous
//
#include <hip/hip_runtime.h>

typedef __attribute__((ext_vector_type(8))) short short8;
typedef __attribute__((ext_vector_type(4))) float f32x4;

constexpr int H = 512, W = 512;
constexpr int P = H * W;     // 262144
constexpr int NSP = 1024;
constexpr int SBLK = 256;    // scatter partial blocks

__device__ inline unsigned short f2bf(float f) {
  unsigned u = __builtin_bit_cast(unsigned, f);
  unsigned r = (u + 0x7fffu + ((u >> 16) & 1u)) >> 16;  // RNE
  return (unsigned short)r;
}

// XCD-band swizzle: 1024 blocks, 8 XCDs round-robin => XCD k owns logical
// ids [k*128,(k+1)*128) = pixel-row band [64k, 64k+64). Producer/consumer
// kernels use the SAME mapping so h1/h2 tiles are read from the writer's L2.
__device__ inline int xcd_swz(int b) { return (b & 7) * 128 + (b >> 3); }

// ---------------- conv1 (+fused weight prep): 1 -> 64, ReLU, NHWC bf16 out ----------------
// Blocks 0..179 additionally transform w2/w3 into staged-order bf16 with the
// baked-in XOR swizzle: chunk k (= tap*2+kc) of 16B-cells; cell t = (row r=t>>2,
// slot'=t&3); stored ic-slot s = slot'^(r&3).
__global__ __launch_bounds__(256) void conv1_k(const float* __restrict__ raw,
                                               const float* __restrict__ w1,
                                               const float* __restrict__ b1,
                                               const float* __restrict__ w2,
                                               const float* __restrict__ w3,
                                               unsigned short* __restrict__ h1,
                                               unsigned short* __restrict__ wt2s,
                                               unsigned short* __restrict__ wt3s,
                                               unsigned short* __restrict__ zeros) {
  int b = blockIdx.x;
  if (b == 0 && threadIdx.x < 128) zeros[threadIdx.x] = 0;  // 256-B zero stub
  if (b < 180) {                       // fused prep (same index math as old prep_k)
    int i = b * 256 + threadIdx.x;
    if (i < 36864) {                   // conv2: 18 chunks x 2048 shorts (64 oc rows)
      int k = i >> 11;
      int t = (i >> 3) & 255;
      int e = i & 7;
      int r = t >> 2, sp = t & 3, s = sp ^ (r & 3);
      int tap = k >> 1, ic = (k & 1) * 32 + s * 8 + e;
      wt2s[i] = f2bf(w2[r * 576 + ic * 9 + tap]);
    } else if (i < 46080) {            // conv3: 18 chunks x 512 shorts (16 rows, 10 real)
      int j = i - 36864;
      int k = j >> 9;
      int t = (j >> 3) & 63;
      int e = j & 7;
      int r = t >> 2, sp = t & 3, s = sp ^ (r & 3);
      int tap = k >> 1, ic = (k & 1) * 32 + s * 8 + e;
      wt3s[j] = (r < 10) ? f2bf(w3[r * 576 + ic * 9 + tap]) : (unsigned short)0;
    }
  }

  int pix = xcd_swz(b) * 256 + threadIdx.x;   // XCD k writes rows [64k,64k+64)
  int r = pix >> 9, c = pix & 511;
  float in[9];
#pragma unroll
  for (int ky = 0; ky < 3; ++ky)
#pragma unroll
    for (int kx = 0; kx < 3; ++kx) {
      int rr = r + ky - 1, cc = c + kx - 1;
      bool ok = ((unsigned)rr < (unsigned)H) && ((unsigned)cc < (unsigned)W);
      in[ky * 3 + kx] = ok ? raw[rr * W + cc] : 0.f;
    }
  unsigned out_u[32];
#pragma unroll
  for (int p2 = 0; p2 < 32; ++p2) {
    float a0 = b1[2 * p2], a1 = b1[2 * p2 + 1];
#pragma unroll
    for (int k = 0; k < 9; ++k) {
      a0 = fmaf(in[k], w1[(2 * p2) * 9 + k], a0);
      a1 = fmaf(in[k], w1[(2 * p2 + 1) * 9 + k], a1);
    }
    a0 = fmaxf(a0, 0.f);
    a1 = fmaxf(a1, 0.f);
    out_u[p2] = (unsigned)f2bf(a0) | ((unsigned)f2bf(a1) << 16);
  }
  uint4* dst = reinterpret_cast<uint4*>(h1 + (size_t)pix * 64);
#pragma unroll
  for (int i = 0; i < 8; ++i)
    dst[i] = make_uint4(out_u[4 * i], out_u[4 * i + 1], out_u[4 * i + 2], out_u[4 * i + 3]);
}

// Shared acts staging: 344-pixel halo tile (340 used), 43 wave-issues of 1 KiB.
// LDS layout: [pix][8 slot'][8 ic] with slot' = slot ^ (pix&7).
__device__ inline void stage_acts(const unsigned short* __restrict__ xin,
                                  const unsigned short* __restrict__ zeros,
                                  unsigned short* acts, int r0, int c0,
                                  int wave, int lane) {
  for (int wi = wave; wi < 43; wi += 4) {
    int cidx = wi * 64 + lane;
    int pix = cidx >> 3, slotp = cidx & 7;
    int prow = pix / 34, pcol = pix - prow * 34;
    int gr = r0 + prow - 1, gc = c0 + pcol - 1;
    int slot = slotp ^ (pix & 7);
    bool ok = (pix < 340) & ((unsigned)gr < 512u) & ((unsigned)gc < 512u);
    const unsigned short* src = ok ? (xin + (((size_t)(gr * 512 + gc)) << 6) + slot * 8) : zeros;
    unsigned short* dstb = &acts[wi * 512];  // wave-uniform base
    __builtin_amdgcn_global_load_lds((const __attribute__((address_space(1))) void*)src,
                                     (__attribute__((address_space(3))) void*)dstb, 16, 0, 0);
  }
}

// ---------------- conv2 (MFMA): 64 -> 64, ReLU, NHWC out; weight ring pipeline ----------------
__global__ __launch_bounds__(256) void conv2_k(const unsigned short* __restrict__ xin,
                                               const unsigned short* __restrict__ wts,
                                               const float* __restrict__ bias,
                                               unsigned short* __restrict__ ynhwc,
                                               const unsigned short* __restrict__ zeros) {
  constexpr int WCS = 2048;                                // chunk shorts (4 KiB)
  __shared__ __align__(16) unsigned short acts[344 * 64];  // 44032 B
  __shared__ __align__(16) unsigned short wbuf[3 * WCS];   // 12288 B
  int tid = threadIdx.x;
  int lane = tid & 63, wave = tid >> 6;
  int logical = xcd_swz(blockIdx.x);
  int tilex = logical & 15, tiley = logical >> 4;
  int c0 = tilex * 32, r0 = tiley * 8;

  stage_acts(xin, zeros, acts, r0, c0, wave, lane);
#pragma unroll
  for (int k0 = 0; k0 < 2; ++k0) {                         // prologue chunks 0,1
    const unsigned short* src = wts + (size_t)k0 * WCS + tid * 8;
    unsigned short* dstb = wbuf + k0 * WCS + wave * 512;
    __builtin_amdgcn_global_load_lds((const __attribute__((address_space(1))) void*)src,
                                     (__attribute__((address_space(3))) void*)dstb, 16, 0, 0);
  }
  __syncthreads();  // full drain — pipeline starts clean

  int q = lane >> 4, n = lane & 15;
  f32x4 acc[4][4];
#pragma unroll
  for (int og = 0; og < 4; ++og)
#pragma unroll
    for (int g = 0; g < 4; ++g) acc[og][g] = (f32x4){0.f, 0.f, 0.f, 0.f};

  int plbase[4];
#pragma unroll
  for (int g = 0; g < 4; ++g)
    plbase[g] = (wave * 2 + (g >> 1)) * 34 + 16 * (g & 1) + n;
  const char* actb = (const char*)acts;

#pragma unroll
  for (int k = 0; k < 18; ++k) {
    asm volatile("s_waitcnt vmcnt(1)" ::: "memory");   // own chunk-k part landed
    __builtin_amdgcn_sched_barrier(0);
    __builtin_amdgcn_s_barrier();                      // all parts landed; NO drain
    __builtin_amdgcn_sched_barrier(0);
    if (k + 2 < 18) {                                  // slot (k+2)%3 free: read at k-1
      const unsigned short* src = wts + (size_t)(k + 2) * WCS + tid * 8;
      unsigned short* dstb = wbuf + ((k + 2) % 3) * WCS + wave * 512;
      __builtin_amdgcn_global_load_lds((const __attribute__((address_space(1))) void*)src,
                                       (__attribute__((address_space(3))) void*)dstb, 16, 0, 0);
    }
    const int tap = k >> 1, kc = k & 1;
    const int kyy = tap / 3, kxx = tap - kyy * 3;
    const char* wb = (const char*)(wbuf + (k % 3) * WCS);
    short8 af[4];
#pragma unroll
    for (int og = 0; og < 4; ++og) {
      int r = og * 16 + n;
      af[og] = *reinterpret_cast<const short8*>(wb + r * 64 + ((q ^ (r & 3)) * 16));
    }
#pragma unroll
    for (int g = 0; g < 4; ++g) {
      int pl = plbase[g] + kyy * 34 + kxx;
      int addr = pl * 128 + (((kc * 4 + q) ^ (pl & 7)) * 16);
      short8 bf = *reinterpret_cast<const short8*>(actb + addr);
#pragma unroll
      for (int og = 0; og < 4; ++og)
        acc[og][g] = __builtin_amdgcn_mfma_f32_16x16x32_bf16(af[og], bf, acc[og][g], 0, 0, 0);
    }
  }

  // ---- epilogue: acc -> LDS (swizzled NHWC tile) -> coalesced 16B stores ----
  __syncthreads();  // acts reads done; safe to reuse as output staging
  char* ob = (char*)acts;
#pragma unroll
  for (int og = 0; og < 4; ++og) {
    float b0 = bias[og * 16 + q * 4 + 0], b1 = bias[og * 16 + q * 4 + 1];
    float b2 = bias[og * 16 + q * 4 + 2], b3 = bias[og * 16 + q * 4 + 3];
#pragma unroll
    for (int g = 0; g < 4; ++g) {
      int pl = wave * 64 + g * 16 + n;
      f32x4 v = acc[og][g];
      float o0 = fmaxf(v.x + b0, 0.f), o1 = fmaxf(v.y + b1, 0.f);
      float o2 = fmaxf(v.z + b2, 0.f), o3 = fmaxf(v.w + b3, 0.f);
      unsigned lo = (unsigned)f2bf(o0) | ((unsigned)f2bf(o1) << 16);
      unsigned hi = (unsigned)f2bf(o2) | ((unsigned)f2bf(o3) << 16);
      int lslot = og * 2 + (q >> 1);                   // logical 16B slot
      int wa = pl * 128 + (((lslot ^ (pl & 7)) << 4)) + ((q & 1) << 3);
      *reinterpret_cast<uint2*>(ob + wa) = make_uint2(lo, hi);
    }
  }
  __syncthreads();
  char* yb = (char*)ynhwc;
#pragma unroll
  for (int it = 0; it < 8; ++it) {
    int c = it * 256 + tid;                            // 2048 16-B chunks
    int pl = c >> 3, slot = c & 7;
    uint4 v = *reinterpret_cast<const uint4*>(ob + pl * 128 + ((slot ^ (pl & 7)) << 4));
    size_t gb = (((size_t)(r0 + (pl >> 5)) * 512) + c0 + (pl & 31)) * 128 + slot * 16;
    *reinterpret_cast<uint4*>(yb + gb) = v;
  }
}

// ---------------- conv3 (MFMA): 64 -> 10, planar f32 out; weights fully LDS-resident ----------------
__global__ __launch_bounds__(256) void conv3_k(const unsigned short* __restrict__ xin,
                                               const unsigned short* __restrict__ wts,
                                               const float* __restrict__ bias,
                                               float* __restrict__ feats,
                                               const unsigned short* __restrict__ zeros) {
  __shared__ __align__(16) unsigned short acts[344 * 64];  // 44032 B
  __shared__ __align__(16) unsigned short wl[9216];        // 18432 B (18 chunks x 1 KiB)
  int tid = threadIdx.x;
  int lane = tid & 63, wave = tid >> 6;
  int logical = xcd_swz(blockIdx.x);
  int tilex = logical & 15, tiley = logical >> 4;
  int c0 = tilex * 32, r0 = tiley * 8;

  stage_acts(xin, zeros, acts, r0, c0, wave, lane);
  for (int wi = wave; wi < 18; wi += 4) {                  // all 18 KB of weights, once
    const unsigned short* src = wts + (size_t)wi * 512 + lane * 8;
    unsigned short* dstb = &wl[wi * 512];
    __builtin_amdgcn_global_load_lds((const __attribute__((address_space(1))) void*)src,
                                     (__attribute__((address_space(3))) void*)dstb, 16, 0, 0);
  }
  __syncthreads();

  int q = lane >> 4, n = lane & 15;
  f32x4 acc[4];
#pragma unroll
  for (int g = 0; g < 4; ++g) acc[g] = (f32x4){0.f, 0.f, 0.f, 0.f};
  int plbase[4];
#pragma unroll
  for (int g = 0; g < 4; ++g)
    plbase[g] = (wave * 2 + (g >> 1)) * 34 + 16 * (g & 1) + n;
  const char* actb = (const char*)acts;
  const char* wb0 = (const char*)wl;

#pragma unroll
  for (int k = 0; k < 18; ++k) {                           // no barriers, no waitcnts
    const int tap = k >> 1, kc = k & 1;
    const int kyy = tap / 3, kxx = tap - kyy * 3;
    short8 af = *reinterpret_cast<const short8*>(wb0 + k * 1024 + n * 64 + ((q ^ (n & 3)) * 16));
#pragma unroll
    for (int g = 0; g < 4; ++g) {
      int pl = plbase[g] + kyy * 34 + kxx;
      int addr = pl * 128 + (((kc * 4 + q) ^ (pl & 7)) * 16);
      short8 bf = *reinterpret_cast<const short8*>(actb + addr);
      acc[g] = __builtin_amdgcn_mfma_f32_16x16x32_bf16(af, bf, acc[g], 0, 0, 0);
    }
  }

  // ---- epilogue: acc -> LDS (stride-48 rows) -> coalesced 8B copies ----
  __syncthreads();
  char* ob = (char*)acts;
  float bb[4];
#pragma unroll
  for (int r2 = 0; r2 < 4; ++r2) {
    int oc = q * 4 + r2;
    bb[r2] = (oc < 10) ? bias[oc] : 0.f;
  }
#pragma unroll
  for (int g = 0; g < 4; ++g) {
    int pl = wave * 64 + g * 16 + n;
    f32x4 v = acc[g];
    float o0 = v.x + bb[0], o1 = v.y + bb[1], o2 = v.z + bb[2], o3 = v.w + bb[3];
    if (q < 2) {
      *reinterpret_cast<f32x4*>(ob + pl * 48 + q * 16) = (f32x4){o0, o1, o2, o3};
    } else if (q == 2) {
      *reinterpret_cast<float2*>(ob + pl * 48 + 32) = make_float2(o0, o1);
    }
  }
  __syncthreads();
  char* fb = (char*)feats;
#pragma unroll
  for (int it = 0; it < 5; ++it) {
    int c = it * 256 + tid;                            // 1280 8-B chunks (8 rows x 1280 B)
    int row = c / 160, ib = (c - row * 160) * 8;
    int px = ib / 40, off = ib - px * 40;
    uint2 v = *reinterpret_cast<const uint2*>(ob + (row * 32 + px) * 48 + off);
    size_t gb = (((size_t)(r0 + row) * 512) + c0) * 40 + (size_t)ib;
    *reinterpret_cast<uint2*>(fb + gb) = v;
  }
}

// ---------------- scatter: LDS accumulate -> per-block partials ----------------
__global__ __launch_bounds__(256) void scatter_k(const float* __restrict__ feats,  // [P][10]
                                                 const int* __restrict__ pix_rc,
                                                 const int* __restrict__ seg,
                                                 float* __restrict__ partials) {
  __shared__ float ls[NSP * 10];
  __shared__ float lc[NSP];
  int tid = threadIdx.x;
  for (int i = tid; i < NSP * 10; i += 256) ls[i] = 0.f;
  for (int i = tid; i < NSP; i += 256) lc[i] = 0.f;
  __syncthreads();

  constexpr int PER = P / SBLK;  // 1024
  int p0 = blockIdx.x * PER;
  for (int p = p0 + tid; p < p0 + PER; p += 256) {
    int r = pix_rc[2 * p], c = pix_rc[2 * p + 1];
    int s = seg[p];
    size_t gpix = (size_t)r * 512 + c;
    const float* fp = feats + gpix * 10;
    float v[10];
#pragma unroll
    for (int h2 = 0; h2 < 5; ++h2) {
      float2 t = *reinterpret_cast<const float2*>(fp + 2 * h2);
      v[2 * h2] = t.x;
      v[2 * h2 + 1] = t.y;
    }
#pragma unroll
    for (int ch = 0; ch < 10; ++ch) atomicAdd(&ls[s * 10 + ch], v[ch]);
    atomicAdd(&lc[s], 1.f);
  }
  __syncthreads();

  float* outp = partials + (size_t)blockIdx.x * (NSP * 11);
  for (int i = tid; i < NSP * 10; i += 256) outp[i] = ls[i];
  for (int i = tid; i < NSP; i += 256) outp[NSP * 10 + i] = lc[i];
}

// ---------------- finalize ----------------
__global__ __launch_bounds__(256) void finalize_k(const float* __restrict__ partials,
                                                  float* __restrict__ out) {
  int i = blockIdx.x * 256 + threadIdx.x;
  if (i >= NSP * 10) return;
  int sp = i / 10;
  float s = 0.f, cnt = 0.f;
  for (int bq = 0; bq < SBLK; ++bq) {
    const float* pp = partials + (size_t)bq * (NSP * 11);
    s += pp[i];
    cnt += pp[NSP * 10 + sp];
  }
  out[i] = s / fmaxf(cnt, 1.f);
}

extern "C" void kernel_launch(void* const* d_in, const int* in_sizes, int n_in,
                              void* d_out, int out_size, void* d_ws, size_t ws_size,
                              hipStream_t stream) {
  const float* raw = (const float*)d_in[0];
  const float* w1  = (const float*)d_in[1];
  const float* b1  = (const float*)d_in[2];
  const float* w2  = (const float*)d_in[3];
  const float* b2  = (const float*)d_in[4];
  const float* w3  = (const float*)d_in[5];
  const float* b3  = (const float*)d_in[6];
  const int* pix_rc = (const int*)d_in[7];
  const int* seg    = (const int*)d_in[8];
  float* out = (float*)d_out;

  char* ws = (char*)d_ws;
  unsigned short* h1   = (unsigned short*)(ws + 0);          // [P][64] bf16, 33.55 MB
  unsigned short* h2   = (unsigned short*)(ws + 33554432);   // [P][64] bf16, 33.55 MB
  float* feats         = (float*)(ws + 67108864);            // [P][10] f32, 10.49 MB
  unsigned short* wt2s = (unsigned short*)(ws + 77594624);   // 36864 shorts = 73728 B
  unsigned short* wt3s = (unsigned short*)(ws + 77668352);   // 9216 shorts = 18432 B
  unsigned short* zeros = (unsigned short*)(ws + 77686784);  // 256 B zero stub
  float* partials      = (float*)(ws + 77687040);            // 256 * 11264 f32

  conv1_k<<<1024, 256, 0, stream>>>(raw, w1, b1, w2, w3, h1, wt2s, wt3s, zeros);
  conv2_k<<<1024, 256, 0, stream>>>(h1, wt2s, b2, h2, zeros);
  conv3_k<<<1024, 256, 0, stream>>>(h2, wt3s, b3, feats, zeros);
  scatter_k<<<SBLK, 256, 0, stream>>>(feats, pix_rc, seg, partials);
  finalize_k<<<40, 256, 0, stream>>>(partials, out);
}